// Round 3
// baseline (477.089 us; speedup 1.0000x reference)
//
#include <hip/hip_runtime.h>
#include <hip/hip_bf16.h>

// Problem constants
#define B_DIM   512
#define IN_DIM  4096
#define OUT_DIM 11008

typedef __bf16 bf16x4 __attribute__((ext_vector_type(4)));
typedef __bf16 bf16x8 __attribute__((ext_vector_type(8)));
typedef float  floatx4 __attribute__((ext_vector_type(4)));

// ---------------------------------------------------------------------------
// Pass 1: x fp32 -> bf16 (tiny: 12 MB traffic, ~2 us)
// ---------------------------------------------------------------------------
__global__ __launch_bounds__(256) void conv_x_kernel(
    const float* __restrict__ x, __bf16* __restrict__ xb) {
  int idx = blockIdx.x * blockDim.x + threadIdx.x;  // quad index
  float4 v = ((const float4*)x)[idx];
  bf16x4 o;
  o[0] = (__bf16)v.x; o[1] = (__bf16)v.y; o[2] = (__bf16)v.z; o[3] = (__bf16)v.w;
  ((bf16x4*)xb)[idx] = o;
}

// ---------------------------------------------------------------------------
// Pass 2: fused QINS-decode + GEMM, v3 (T3-minimum pipeline).
// Changes vs v2 (214 us, 11.3M conflicts, ~4000 cyc/tile stall-bound):
//  - ONE barrier + ONE counted s_waitcnt vmcnt(4) per K-tile (was 2 barriers
//    + lgkm drain mid-path). All loads issued early: A(t+1) gl_lds 1 ahead
//    (A is L2-resident), B(t+3) regs 2 ahead (HBM cover ~2 iters).
//  - sA AND sB double-buffered (24 KB LDS total).
//  - Conflict-free LDS via k-slot XOR swizzle f(r)=(r^(r>>2))&3 on BOTH
//    sides (A: pre-swizzled global source per m173; B: swizzled ds_write).
//    Verified uniform 8 lanes/bank-quad (= b128 minimum) for all accesses.
//  - sched_barrier(0) pins so the vmcnt(4) queue-order math holds.
// ---------------------------------------------------------------------------
__device__ __forceinline__ void gl_lds16(const __bf16* g, __bf16* l) {
  __builtin_amdgcn_global_load_lds(
      (const __attribute__((address_space(1))) void*)g,
      (__attribute__((address_space(3))) void*)l, 16, 0, 0);
}

// w = sign * exp(lmin + (255 - s)/254 * (lmax-lmin))  (numerics unchanged)
__device__ __forceinline__ __bf16 dec1(int s, int g, float lmin, float slope) {
  return (__bf16)(__expf(lmin + (float)(255 - s) * slope) * (float)g);
}

__device__ __forceinline__ bf16x8 dec8(int4 sl, int4 sh, int4 gl, int4 gh,
                                       float lmin, float slope) {
  bf16x8 w;
  w[0] = dec1(sl.x, gl.x, lmin, slope);
  w[1] = dec1(sl.y, gl.y, lmin, slope);
  w[2] = dec1(sl.z, gl.z, lmin, slope);
  w[3] = dec1(sl.w, gl.w, lmin, slope);
  w[4] = dec1(sh.x, gh.x, lmin, slope);
  w[5] = dec1(sh.y, gh.y, lmin, slope);
  w[6] = dec1(sh.z, gh.z, lmin, slope);
  w[7] = dec1(sh.w, gh.w, lmin, slope);
  return w;
}

__global__ __launch_bounds__(256, 2) void fused_qins_gemm_kernel(
    const __bf16* __restrict__ A,      // 512 x 4096 bf16 (pre-converted x)
    const int* __restrict__ stored,    // 11008 x 4096 int32 in [1,255]
    const int* __restrict__ sign,      // 11008 x 4096 int32 +-1
    const float* __restrict__ logmin, const float* __restrict__ logmax,
    const float* __restrict__ scale, const float* __restrict__ bias,
    float* __restrict__ out) {
  constexpr int K = IN_DIM, N = OUT_DIM;
  constexpr int BK = 32;
  constexpr int NIT = K / BK;          // 128 k-tiles

  __shared__ __align__(16) __bf16 sA[2][128 * BK];  // 2 x 8 KB
  __shared__ __align__(16) __bf16 sB[2][64 * BK];   // 2 x 4 KB

  const int tid  = threadIdx.x;
  const int lane = tid & 63;
  const int wave = tid >> 6;
  const int wm   = (wave >> 1) * 64;   // wave M offset (0/64)
  const int wn   = (wave & 1) * 32;    // wave N offset (0/32)
  const int m16  = lane & 15;
  const int q    = lane >> 4;          // 0..3

  // XCD-grouped swizzle: 688 = 8 XCDs x 86; bm fastest so the 4 blocks
  // sharing a bn panel co-reside on one XCD (stored/sign reuse hits L2).
  const int wg  = blockIdx.x;                 // 0..687
  const int g   = (wg & 7) * 86 + (wg >> 3);  // bijective
  const int bm0 = (g & 3) * 128;              // 4 M-tiles
  const int bn0 = (g >> 2) * 64;              // 172 N-tiles

  const float lmin  = logmin[0];
  const float slope = (logmax[0] - lmin) * (1.0f / 254.0f);

  // LDS swizzle: LDS[row][slot] holds global k-chunk (slot ^ f(row)),
  // f(r) = (r ^ (r>>2)) & 3. Invariant under row+16/row+32/row+64, so the
  // frag-read slot depends only on m16 (lane-constant).
  const int rS = tid >> 2;                    // staging row 0..63
  const int cS = tid & 3;                     // this thread's k-chunk
  const int fS = (rS ^ (rS >> 2)) & 3;
  const int wSlot = cS ^ fS;                  // swizzled slot for chunk cS
  const int rdSlot = q ^ ((m16 ^ (m16 >> 2)) & 3);  // read slot for chunk q

  // A staging: gl_lds writes linearly at tid*16B = (row rS, slot cS) ->
  // pre-swizzle the GLOBAL source so slot cS receives chunk cS ^ f(rS).
  const __bf16* gA0 = A + (size_t)(bm0 + rS) * K + wSlot * 8;
  const __bf16* gA1 = A + (size_t)(bm0 + rS + 64) * K + wSlot * 8;

  // B staging: 8 elems/thread (row rS, chunk cS); write to swizzled slot.
  const int* pS = stored + (size_t)(bn0 + rS) * K + cS * 8;
  const int* pG = sign   + (size_t)(bn0 + rS) * K + cS * 8;
  const int wOff = rS * BK + wSlot * 8;

  floatx4 acc[4][2] = {};

  // ---- Prologue: B(0) decode -> sB[0]; issue A(0); load B(1),B(2); drain.
  {
    int4 ps0 = ((const int4*)pS)[0], ps1 = ((const int4*)pS)[1];
    int4 pg0 = ((const int4*)pG)[0], pg1 = ((const int4*)pG)[1];
    bf16x8 w = dec8(ps0, ps1, pg0, pg1, lmin, slope);
    *(bf16x8*)&sB[0][wOff] = w;
  }
  gl_lds16(gA0, &sA[0][tid * 8]);
  gl_lds16(gA1, &sA[0][2048 + tid * 8]);
  int4 s0a = ((const int4*)(pS + BK))[0],     s1a = ((const int4*)(pS + BK))[1];
  int4 g0a = ((const int4*)(pG + BK))[0],     g1a = ((const int4*)(pG + BK))[1];
  int4 s0b = ((const int4*)(pS + 2 * BK))[0], s1b = ((const int4*)(pS + 2 * BK))[1];
  int4 g0b = ((const int4*)(pG + 2 * BK))[0], g1b = ((const int4*)(pG + 2 * BK))[1];
  asm volatile("s_waitcnt vmcnt(0) lgkmcnt(0)" ::: "memory");

  // Per tile t: wait vmcnt(4) retires {B(t+1) [issued t-2], A(t) [t-1]} and
  // leaves B(t+2) in flight. barrier -> ds_read(t) -> decode B(t+1) ->
  // ds_write sB[nxt] -> issue A(t+1), B(t+3) -> lgkm -> MFMA. ONE barrier.
#define STEP(T, CUR, NXT, S0, S1, G0, G1)                                     \
  {                                                                           \
    asm volatile("s_waitcnt vmcnt(4)" ::: "memory");                          \
    __builtin_amdgcn_s_barrier();                                             \
    __builtin_amdgcn_sched_barrier(0);                                        \
    bf16x8 afr[4], bfr[2];                                                    \
    _Pragma("unroll")                                                         \
    for (int ii = 0; ii < 4; ++ii)                                            \
      afr[ii] = *(const bf16x8*)&sA[CUR][(wm + ii * 16 + m16) * BK +          \
                                         rdSlot * 8];                         \
    _Pragma("unroll")                                                         \
    for (int ii = 0; ii < 2; ++ii)                                            \
      bfr[ii] = *(const bf16x8*)&sB[CUR][(wn + ii * 16 + m16) * BK +          \
                                         rdSlot * 8];                         \
    bf16x8 w = dec8(S0, S1, G0, G1, lmin, slope);                             \
    *(bf16x8*)&sB[NXT][wOff] = w;                                             \
    __builtin_amdgcn_sched_barrier(0);                                        \
    {                                                                         \
      const int ktA = ((T) + 1 < NIT) ? ((T) + 1) * BK : 0;                   \
      gl_lds16(gA0 + ktA, &sA[NXT][tid * 8]);                                 \
      gl_lds16(gA1 + ktA, &sA[NXT][2048 + tid * 8]);                          \
    }                                                                         \
    __builtin_amdgcn_sched_barrier(0);                                        \
    {                                                                         \
      const int ktB = ((T) + 3 < NIT) ? ((T) + 3) * BK : 0;                   \
      S0 = ((const int4*)(pS + ktB))[0];                                      \
      S1 = ((const int4*)(pS + ktB))[1];                                      \
      G0 = ((const int4*)(pG + ktB))[0];                                      \
      G1 = ((const int4*)(pG + ktB))[1];                                      \
    }                                                                         \
    asm volatile("s_waitcnt lgkmcnt(0)" ::: "memory");                        \
    __builtin_amdgcn_sched_barrier(0);                                        \
    _Pragma("unroll")                                                         \
    for (int mi = 0; mi < 4; ++mi)                                            \
      _Pragma("unroll")                                                       \
      for (int ni = 0; ni < 2; ++ni)                                          \
        acc[mi][ni] = __builtin_amdgcn_mfma_f32_16x16x32_bf16(                \
            afr[mi], bfr[ni], acc[mi][ni], 0, 0, 0);                          \
  }

  for (int t = 0; t < NIT; t += 2) {
    STEP(t,     0, 1, s0a, s1a, g0a, g1a);  // even t: set A holds B(t+1)
    STEP(t + 1, 1, 0, s0b, s1b, g0b, g1b);  // odd t:  set B holds B(t+1)
  }
#undef STEP

  // Epilogue. C/D layout: col = lane&15, row = q*4 + reg  [m89]
#pragma unroll
  for (int ni = 0; ni < 2; ++ni) {
    const int col = bn0 + wn + ni * 16 + m16;
    const float sc = scale[col];
    const float bb = bias[col] * sc;
#pragma unroll
    for (int mi = 0; mi < 4; ++mi) {
#pragma unroll
      for (int r = 0; r < 4; ++r) {
        const int row = bm0 + wm + mi * 16 + q * 4 + r;
        out[row * N + col] = acc[mi][ni][r] * sc + bb;
      }
    }
  }
}

// ---------------------------------------------------------------------------
extern "C" void kernel_launch(void* const* d_in, const int* in_sizes, int n_in,
                              void* d_out, int out_size, void* d_ws, size_t ws_size,
                              hipStream_t stream) {
  const float* x      = (const float*)d_in[0];
  const int*   stored = (const int*)d_in[1];
  const int*   sign   = (const int*)d_in[2];
  const float* logmin = (const float*)d_in[3];
  const float* logmax = (const float*)d_in[4];
  const float* scale  = (const float*)d_in[5];
  const float* bias   = (const float*)d_in[6];
  float* out = (float*)d_out;

  __bf16* wsX = (__bf16*)d_ws;  // 512*4096 bf16 = 4 MB

  conv_x_kernel<<<2048, 256, 0, stream>>>(x, wsX);
  // 172 bn-tiles x 4 bm-tiles = 688 blocks (XCD-swizzled)
  fused_qins_gemm_kernel<<<688, 256, 0, stream>>>(
      wsX, stored, sign, logmin, logmax, scale, bias, out);
}